// Round 7
// baseline (373.351 us; speedup 1.0000x reference)
//
#include <hip/hip_runtime.h>
#include <hip/hip_bf16.h>

#define NN 8192
constexpr int   STEPS = 10;
constexpr float ALPHA = 0.5f;
constexpr float EPSV  = 1e-10f;

typedef float f32x2 __attribute__((ext_vector_type(2)));
typedef float f32x4 __attribute__((ext_vector_type(4)));

static __device__ __forceinline__ unsigned int f2bf(float f) {
    unsigned int u = __float_as_uint(f);
    return (u + 0x7FFFu + ((u >> 16) & 1u)) >> 16;
}
static __device__ __forceinline__ float bf2f(unsigned int h) {
    return __uint_as_float(h << 16);
}

// ---- Fused: updated_adj = M*adj (nt), adj->fp8 copy, rowsum. One row/block ----
// Near fabric-roofline — unchanged.
__global__ __launch_bounds__(256) void k_fused_prep(
        const float* __restrict__ adj, const float* __restrict__ M,
        float* __restrict__ out, unsigned char* __restrict__ a8,
        float* __restrict__ rowsum) {
    const int row = blockIdx.x;
    const int t   = threadIdx.x;
    const float* arow = adj + (size_t)row * NN;
    const float* mrow = M   + (size_t)row * NN;
    float*       orow = out + (size_t)row * NN;
    unsigned char* brow = a8 + (size_t)row * NN;
    float acc = 0.0f;
#pragma unroll
    for (int g = 0; g < 2; ++g) {
        f32x4 v[4], m[4];
#pragma unroll
        for (int k = 0; k < 4; ++k) {
            const int j = (g * 4 + k) * 1024 + t * 4;
            v[k] = __builtin_nontemporal_load((const f32x4*)(arow + j));
        }
#pragma unroll
        for (int k = 0; k < 4; ++k) {
            const int j = (g * 4 + k) * 1024 + t * 4;
            m[k] = __builtin_nontemporal_load((const f32x4*)(mrow + j));
        }
#pragma unroll
        for (int k = 0; k < 4; ++k) {
            const int j = (g * 4 + k) * 1024 + t * 4;
            f32x4 r = v[k] * m[k];
            __builtin_nontemporal_store(r, (f32x4*)(orow + j));
            acc += (v[k].x + v[k].y) + (v[k].z + v[k].w);
            int p = __builtin_amdgcn_cvt_pk_fp8_f32(v[k].x, v[k].y, 0, false);
            p     = __builtin_amdgcn_cvt_pk_fp8_f32(v[k].z, v[k].w, p, true);
            *(unsigned int*)(brow + j) = (unsigned int)p;
        }
    }
#pragma unroll
    for (int o = 32; o > 0; o >>= 1) acc += __shfl_down(acc, o);
    __shared__ float red[4];
    if ((t & 63) == 0) red[t >> 6] = acc;
    __syncthreads();
    if (t == 0) rowsum[row] = (red[0] + red[1]) + (red[2] + red[3]);
}

// ---- tiny capture-safe zeroing kernel (flags + done + accs = 2KB) ----
__global__ __launch_bounds__(512) void k_zero(unsigned int* __restrict__ p) {
    p[threadIdx.x] = 0u;
}

// ================= Persistent chain (single regular launch) =================
// 256 blocks x 512 threads, 1 block/CU (132KB LDS), co-resident by
// construction. KEY CHANGE (round 6 post-mortem): 256 threads/block meant
// 1 wave/SIMD -> zero TLP -> every z/MALL/ds/shfl latency fully exposed;
// three barrier variants all plateaued ~21us/step. 512 threads = 2 waves/SIMD
// doubles latency overlap. Per thread: 16B row slice; pa[16] regs (64 VGPR),
// 16 rows in LDS. Barrier = round-5 flags+done (measured best).
#define CBLK  256
#define CTHR  512
#define CROWS 32
#define RREG  16
#define RLDS  16

static __device__ __forceinline__ void gbar(unsigned int* flags,
                                            unsigned int* done,
                                            unsigned int phase) {
    __syncthreads();   // all waves' z stores vmcnt-drained before arrival
    const int t = threadIdx.x;
    if (t == 0)
        __hip_atomic_store(&flags[blockIdx.x], phase, __ATOMIC_RELEASE,
                           __HIP_MEMORY_SCOPE_AGENT);
    if (blockIdx.x == 0) {
        if (t < CBLK) {   // each watcher owns one block's flag — RELAXED polls
            const long long t0 = clock64();
            while (__hip_atomic_load(&flags[t], __ATOMIC_RELAXED,
                                     __HIP_MEMORY_SCOPE_AGENT) < phase) {
                __builtin_amdgcn_s_sleep(1);
                if (clock64() - t0 > 300000000LL) break;   // anti-hang valve
            }
        }
        __syncthreads();                                   // all 256 seen
        if (t == 0)
            __hip_atomic_store(done, phase, __ATOMIC_RELEASE,
                               __HIP_MEMORY_SCOPE_AGENT);
    }
    if (t == 0) {
        const long long t0 = clock64();
        while (__hip_atomic_load(done, __ATOMIC_RELAXED,
                                 __HIP_MEMORY_SCOPE_AGENT) < phase) {
            __builtin_amdgcn_s_sleep(1);
            if (clock64() - t0 > 300000000LL) break;       // anti-hang valve
        }
        // ONE acquire per block per barrier (fence + invalidate)
        (void)__hip_atomic_load(done, __ATOMIC_ACQUIRE, __HIP_MEMORY_SCOPE_AGENT);
    }
    __syncthreads();
}

// chunk swizzle: 16B chunk c stored at slot c ^ ((c>>3)&7) (bijective per
// 64-chunk group; same map on write+read; spreads wave reads over banks).
static __device__ __forceinline__ int lds_off(int r, int c) {
    return r * 8192 + ((c ^ ((c >> 3) & 7)) << 4);
}

#define FMA_WORD(w, m)                                                \
    { f32x2 lo = __builtin_amdgcn_cvt_pk_f32_fp8((int)(w), false);    \
      f32x2 hi = __builtin_amdgcn_cvt_pk_f32_fp8((int)(w), true);     \
      a01 += lo * zf2[(m)];                                           \
      a23 += hi * zf2[(m) + 1]; }

#define DOT_ROW4(q, res)                                              \
    { f32x2 a01 = {0.f, 0.f}, a23 = {0.f, 0.f};                       \
      FMA_WORD(q.x, 0)  FMA_WORD(q.y, 2)                              \
      FMA_WORD(q.z, 4)  FMA_WORD(q.w, 6)                              \
      res = (a01[0] + a01[1]) + (a23[0] + a23[1]); }

__global__ __launch_bounds__(512, 1) void k_chain(
        const unsigned char* __restrict__ a8, const float* __restrict__ rowsum,
        const float* __restrict__ pos,
        unsigned int* __restrict__ z_a, unsigned int* __restrict__ z_b,
        unsigned int* __restrict__ flags, unsigned int* __restrict__ done,
        float* __restrict__ accs, float* __restrict__ loss_out) {
    const int t  = threadIdx.x;          // 0..511 (8 waves)
    const int b  = blockIdx.x;
    const int r0 = b * CROWS;

    __shared__ __align__(16) unsigned char lds_a[RLDS * 8192];   // 128 KB
    __shared__ float xloc[CROWS], dloc[CROWS], ploc[CROWS];
    __shared__ unsigned short zs[CROWS];
    __shared__ float red[CROWS][8];

    // ---- init: this block's 32 rows ----
    if (t < CROWS) {
        const int row = r0 + t;
        const float dv = rsqrtf(rowsum[row]);
        const float pv = pos[row];
        const float xv = 1.0f - pv;
        dloc[t] = dv; ploc[t] = pv; xloc[t] = xv;
        zs[t] = (unsigned short)f2bf(dv * xv);
    }
    __syncthreads();
    if (t < CROWS / 2) {
        unsigned int w = (unsigned)zs[2 * t] | ((unsigned)zs[2 * t + 1] << 16);
        __hip_atomic_store(&z_a[r0 / 2 + t], w, __ATOMIC_RELAXED,
                           __HIP_MEMORY_SCOPE_AGENT);
    }

    // ---- stage A: rows 0..15 into registers, rows 16..31 into LDS ----
    const int j = t * 16;               // byte offset of this thread's slice
    uint4 pa[RREG];
#pragma unroll
    for (int r = 0; r < RREG; ++r) {
        pa[r] = *(const uint4*)(a8 + (size_t)(r0 + r) * NN + j);
    }
#pragma unroll
    for (int g = 0; g < 4; ++g) {
        uint4 v[4];
#pragma unroll
        for (int rr = 0; rr < 4; ++rr) {
            v[rr] = *(const uint4*)(a8 + (size_t)(r0 + RREG + g * 4 + rr) * NN + j);
        }
#pragma unroll
        for (int rr = 0; rr < 4; ++rr) {
            *(uint4*)&lds_a[lds_off(g * 4 + rr, t)] = v[rr];
        }
    }
    gbar(flags, done, 1u);

    const unsigned int* zi = z_a;
    unsigned int*       zo = z_b;
#pragma unroll 1
    for (int s = 0; s < STEPS; ++s) {
        // z slice: 2 coalesced plain uint4 loads (fresh after gbar's acquire)
        f32x2 zf2[8];
        {
            const uint4* zv = (const uint4*)(zi + t * 8);
            uint4 zq[2];
            zq[0] = zv[0]; zq[1] = zv[1];
#pragma unroll
            for (int k = 0; k < 2; ++k) {
                const unsigned int ww[4] = {zq[k].x, zq[k].y, zq[k].z, zq[k].w};
#pragma unroll
                for (int m = 0; m < 4; ++m) {
                    f32x2 p;
                    p[0] = bf2f(ww[m] & 0xFFFFu);
                    p[1] = bf2f(ww[m] >> 16);
                    zf2[k * 4 + m] = p;
                }
            }
        }
        // ---- phase A: 16 register-resident rows ----
        float accA[RREG];
#pragma unroll
        for (int r = 0; r < RREG; ++r) {
            DOT_ROW4(pa[r], accA[r]);
        }
#pragma unroll
        for (int r = 0; r < RREG; ++r) {
#pragma unroll
            for (int o = 32; o > 0; o >>= 1) accA[r] += __shfl_down(accA[r], o);
        }
        if ((t & 63) == 0) {
            const int w = t >> 6;
#pragma unroll
            for (int r = 0; r < RREG; ++r) red[r][w] = accA[r];
        }
        // ---- phase B: 16 LDS-resident rows ----
        float accB[RLDS];
#pragma unroll
        for (int r = 0; r < RLDS; ++r) {
            const uint4 q = *(const uint4*)&lds_a[lds_off(r, t)];
            DOT_ROW4(q, accB[r]);
            if ((r & 7) == 7) __builtin_amdgcn_sched_barrier(0);  // cap hoisting
        }
#pragma unroll
        for (int r = 0; r < RLDS; ++r) {
#pragma unroll
            for (int o = 32; o > 0; o >>= 1) accB[r] += __shfl_down(accB[r], o);
        }
        if ((t & 63) == 0) {
            const int w = t >> 6;
#pragma unroll
            for (int r = 0; r < RLDS; ++r) red[RREG + r][w] = accB[r];
        }
        __syncthreads();
        if (t < CROWS) {
            const float y = ((red[t][0] + red[t][1]) + (red[t][2] + red[t][3]))
                          + ((red[t][4] + red[t][5]) + (red[t][6] + red[t][7]));
            const float dv = dloc[t];
            const float xn = ALPHA * dv * y + (1.0f - ALPHA) * xloc[t];
            xloc[t] = xn;
            zs[t] = (unsigned short)f2bf(dv * xn);
        }
        __syncthreads();
        if (s < STEPS - 1) {
            if (t < CROWS / 2) {
                unsigned int w = (unsigned)zs[2 * t] | ((unsigned)zs[2 * t + 1] << 16);
                __hip_atomic_store(&zo[r0 / 2 + t], w, __ATOMIC_RELAXED,
                                   __HIP_MEMORY_SCOPE_AGENT);
            }
            gbar(flags, done, (unsigned)(2 + s));
            const unsigned int* tz = zi; zi = zo; zo = (unsigned int*)tz;
        }
    }

    // ---- loss: block partial, atomic combine, last block divides ----
    if (t < CROWS) {
        const float xn = xloc[t];
        red[t][0] = ploc[t] * logf(1.0f - xn + EPSV);
        red[t][1] = ploc[t];
    }
    __syncthreads();
    if (t == 0) {
        float n = 0.0f, dd = 0.0f;
#pragma unroll
        for (int r = 0; r < CROWS; ++r) { n += red[r][0]; dd += red[r][1]; }
        atomicAdd(&accs[0], n);
        atomicAdd(&accs[1], dd);
        unsigned int tk = __hip_atomic_fetch_add((unsigned int*)&accs[2], 1u,
                                                 __ATOMIC_ACQ_REL,
                                                 __HIP_MEMORY_SCOPE_AGENT);
        if (tk == CBLK - 1) {
            float sn = __hip_atomic_load(&accs[0], __ATOMIC_RELAXED,
                                         __HIP_MEMORY_SCOPE_AGENT);
            float sd = __hip_atomic_load(&accs[1], __ATOMIC_RELAXED,
                                         __HIP_MEMORY_SCOPE_AGENT);
            loss_out[0] = -sn / sd;
        }
    }
}

// ===================== Fallback path (f32, no-fp8-workspace only) =====================
__global__ __launch_bounds__(256) void k_rowsum(
        const float* __restrict__ adj, float* __restrict__ rowsum) {
    const int row = blockIdx.x;
    const int t   = threadIdx.x;
    const float* arow = adj + (size_t)row * NN;
    float acc = 0.0f;
#pragma unroll
    for (int c = 0; c < 8; ++c) {
        const int j = c * 1024 + t * 4;
        float4 v = *(const float4*)(arow + j);
        acc += (v.x + v.y) + (v.z + v.w);
    }
#pragma unroll
    for (int o = 32; o > 0; o >>= 1) acc += __shfl_down(acc, o);
    __shared__ float red[4];
    if ((t & 63) == 0) red[t >> 6] = acc;
    __syncthreads();
    if (t == 0) rowsum[row] = (red[0] + red[1]) + (red[2] + red[3]);
}

__global__ __launch_bounds__(256) void k_init(
        const float* __restrict__ rowsum, const float* __restrict__ pos,
        float* __restrict__ d, float* __restrict__ x, float* __restrict__ zf) {
    const int i = blockIdx.x * 256 + threadIdx.x;
    const float dv = rsqrtf(rowsum[i]);
    const float xv = 1.0f - pos[i];
    d[i] = dv;
    x[i] = xv;
    zf[i] = dv * xv;
}

__global__ __launch_bounds__(256) void k_step_f32(
        const float* __restrict__ adj, const float* __restrict__ d,
        const float* __restrict__ xin, const float* __restrict__ zin,
        float* __restrict__ xout, float* __restrict__ zout) {
    const int row = blockIdx.x;
    const int t   = threadIdx.x;
    const float* arow = adj + (size_t)row * NN;
    float acc = 0.0f;
#pragma unroll
    for (int c = 0; c < 8; ++c) {
        const int j = c * 1024 + t * 4;
        float4 a = *(const float4*)(arow + j);
        float4 z = *(const float4*)(zin + j);
        acc = fmaf(a.x, z.x, acc); acc = fmaf(a.y, z.y, acc);
        acc = fmaf(a.z, z.z, acc); acc = fmaf(a.w, z.w, acc);
    }
#pragma unroll
    for (int o = 32; o > 0; o >>= 1) acc += __shfl_down(acc, o);
    __shared__ float red[4];
    if ((t & 63) == 0) red[t >> 6] = acc;
    __syncthreads();
    if (t == 0) {
        const float y  = (red[0] + red[1]) + (red[2] + red[3]);
        const float dv = d[row];
        const float xn = ALPHA * dv * y + (1.0f - ALPHA) * xin[row];
        xout[row] = xn;
        zout[row] = dv * xn;
    }
}

__global__ __launch_bounds__(256) void k_mul(
        const float* __restrict__ adj, const float* __restrict__ M,
        float* __restrict__ out) {
    size_t i = ((size_t)blockIdx.x * blockDim.x + threadIdx.x) * 4;
    const size_t stride = (size_t)gridDim.x * blockDim.x * 4;
    const size_t total = (size_t)NN * NN;
    for (; i < total; i += stride) {
        float4 a = *(const float4*)(adj + i);
        float4 m = *(const float4*)(M + i);
        float4 r;
        r.x = a.x * m.x; r.y = a.y * m.y; r.z = a.z * m.z; r.w = a.w * m.w;
        *(float4*)(out + i) = r;
    }
}

__global__ __launch_bounds__(1024) void k_loss(
        const float* __restrict__ pos, const float* __restrict__ xfin,
        float* __restrict__ out) {
    const int t = threadIdx.x;
    float sn = 0.0f, sd = 0.0f;
#pragma unroll
    for (int c = 0; c < 8; ++c) {
        const int i4 = c * 1024 + t;
        float4 p = *(const float4*)(pos  + i4 * 4);
        float4 x = *(const float4*)(xfin + i4 * 4);
        sn += p.x * logf(1.0f - x.x + EPSV);
        sn += p.y * logf(1.0f - x.y + EPSV);
        sn += p.z * logf(1.0f - x.z + EPSV);
        sn += p.w * logf(1.0f - x.w + EPSV);
        sd += (p.x + p.y) + (p.z + p.w);
    }
#pragma unroll
    for (int o = 32; o > 0; o >>= 1) {
        sn += __shfl_down(sn, o);
        sd += __shfl_down(sd, o);
    }
    __shared__ float rn[16], rd[16];
    if ((t & 63) == 0) { rn[t >> 6] = sn; rd[t >> 6] = sd; }
    __syncthreads();
    if (t == 0) {
        float n = 0.0f, dd = 0.0f;
#pragma unroll
        for (int k = 0; k < 16; ++k) { n += rn[k]; dd += rd[k]; }
        out[0] = -n / dd;
    }
}

extern "C" void kernel_launch(void* const* d_in, const int* in_sizes, int n_in,
                              void* d_out, int out_size, void* d_ws, size_t ws_size,
                              hipStream_t stream) {
    const float* adj = (const float*)d_in[0];
    const float* pos = (const float*)d_in[1];
    const float* M   = (const float*)d_in[2];
    float* out = (float*)d_out;

    char* ws = (char*)d_ws;
    float* d_vec  = (float*)(ws + 0);
    float* rowsum = (float*)(ws + 32768);
    float* x_a    = (float*)(ws + 65536);
    float* x_b    = (float*)(ws + 98304);
    unsigned int* z_a    = (unsigned int*)(ws + 131072);   // 16 KB used
    unsigned int* z_b    = (unsigned int*)(ws + 163840);   // 16 KB used
    unsigned int* flags  = (unsigned int*)(ws + 196608);   // 256 dwords
    unsigned int* done   = (unsigned int*)(ws + 196608 + 1024);
    float*        accs   = (float*)(ws + 196608 + 1280);   // sn, sd, ticket
    float* zf_a   = (float*)(ws + 212992);                 // f32 fallback only
    float* zf_b   = (float*)(ws + 229376);
    unsigned char* a8 = (unsigned char*)(ws + 262144);

    const size_t need_fp8 = 262144 + (size_t)NN * NN;
    const bool use_fp8 = (ws_size >= need_fp8);

    if (use_fp8) {
        // Co-residency by construction: 132KB LDS -> 1 block/CU, 256 blocks
        // on 256 CUs (512 threads = 8 waves/CU = 2 waves/SIMD).
        k_zero<<<1, 512, 0, stream>>>((unsigned int*)(ws + 196608));
        k_fused_prep<<<NN, 256, 0, stream>>>(adj, M, out, a8, rowsum);
        k_chain<<<CBLK, CTHR, 0, stream>>>(a8, rowsum, pos, z_a, z_b,
                                           flags, done, accs,
                                           out + (size_t)NN * NN);
        return;
    }

    // -------- fallback: f32 multi-launch path (tiny workspace only) --------
    k_rowsum<<<NN, 256, 0, stream>>>(adj, rowsum);
    k_init<<<NN / 256, 256, 0, stream>>>(rowsum, pos, d_vec, x_a, zf_a);
    float* xi = x_a; float* xo = x_b;
    float* zfi = zf_a; float* zfo = zf_b;
    for (int s = 0; s < STEPS; ++s) {
        k_step_f32<<<NN, 256, 0, stream>>>(adj, d_vec, xi, zfi, xo, zfo);
        float* tz = zfi; zfi = zfo; zfo = tz;
        float* t = xi; xi = xo; xo = t;
    }
    k_mul<<<2048, 256, 0, stream>>>(adj, M, out);
    k_loss<<<1, 1024, 0, stream>>>(pos, xi, out + (size_t)NN * NN);
}

// Round 8
// 261.862 us; speedup vs baseline: 1.4258x; 1.4258x over previous
//
#include <hip/hip_runtime.h>
#include <hip/hip_bf16.h>

#define NN 8192
constexpr int   STEPS = 10;
constexpr float ALPHA = 0.5f;
constexpr float EPSV  = 1e-10f;

typedef float f32x2 __attribute__((ext_vector_type(2)));
typedef float f32x4 __attribute__((ext_vector_type(4)));

static __device__ __forceinline__ unsigned int f2bf(float f) {
    unsigned int u = __float_as_uint(f);
    return (u + 0x7FFFu + ((u >> 16) & 1u)) >> 16;
}
static __device__ __forceinline__ float bf2f(unsigned int h) {
    return __uint_as_float(h << 16);
}

// ---- Fused: updated_adj = M*adj (nt), adj->fp8 copy, rowsum. One row/block ----
// 871 MB aggregate at 5.7 TB/s = 153.5us (measured, round 0). Near the
// ~6.3 TB/s fabric ceiling; all bytes mandatory.
__global__ __launch_bounds__(256) void k_fused_prep(
        const float* __restrict__ adj, const float* __restrict__ M,
        float* __restrict__ out, unsigned char* __restrict__ a8,
        float* __restrict__ rowsum) {
    const int row = blockIdx.x;
    const int t   = threadIdx.x;
    const float* arow = adj + (size_t)row * NN;
    const float* mrow = M   + (size_t)row * NN;
    float*       orow = out + (size_t)row * NN;
    unsigned char* brow = a8 + (size_t)row * NN;
    float acc = 0.0f;
#pragma unroll
    for (int g = 0; g < 2; ++g) {
        f32x4 v[4], m[4];
#pragma unroll
        for (int k = 0; k < 4; ++k) {
            const int j = (g * 4 + k) * 1024 + t * 4;
            v[k] = __builtin_nontemporal_load((const f32x4*)(arow + j));
        }
#pragma unroll
        for (int k = 0; k < 4; ++k) {
            const int j = (g * 4 + k) * 1024 + t * 4;
            m[k] = __builtin_nontemporal_load((const f32x4*)(mrow + j));
        }
#pragma unroll
        for (int k = 0; k < 4; ++k) {
            const int j = (g * 4 + k) * 1024 + t * 4;
            f32x4 r = v[k] * m[k];
            __builtin_nontemporal_store(r, (f32x4*)(orow + j));
            acc += (v[k].x + v[k].y) + (v[k].z + v[k].w);
            int p = __builtin_amdgcn_cvt_pk_fp8_f32(v[k].x, v[k].y, 0, false);
            p     = __builtin_amdgcn_cvt_pk_fp8_f32(v[k].z, v[k].w, p, true);
            *(unsigned int*)(brow + j) = (unsigned int)p;
        }
    }
#pragma unroll
    for (int o = 32; o > 0; o >>= 1) acc += __shfl_down(acc, o);
    __shared__ float red[4];
    if ((t & 63) == 0) red[t >> 6] = acc;
    __syncthreads();
    if (t == 0) rowsum[row] = (red[0] + red[1]) + (red[2] + red[3]);
}

// ---- Fallback pass 1: row sums only ----
__global__ __launch_bounds__(256) void k_rowsum(
        const float* __restrict__ adj, float* __restrict__ rowsum) {
    const int row = blockIdx.x;
    const int t   = threadIdx.x;
    const float* arow = adj + (size_t)row * NN;
    float acc = 0.0f;
#pragma unroll
    for (int c = 0; c < 8; ++c) {
        const int j = c * 1024 + t * 4;
        float4 v = *(const float4*)(arow + j);
        acc += (v.x + v.y) + (v.z + v.w);
    }
#pragma unroll
    for (int o = 32; o > 0; o >>= 1) acc += __shfl_down(acc, o);
    __shared__ float red[4];
    if ((t & 63) == 0) red[t >> 6] = acc;
    __syncthreads();
    if (t == 0) rowsum[row] = (red[0] + red[1]) + (red[2] + red[3]);
}

// ---- init: d = rowsum^-1/2, x0 = 1-pos, z0 = bf16(d*x0) (+f32 copy) ----
__global__ __launch_bounds__(256) void k_init(
        const float* __restrict__ rowsum, const float* __restrict__ pos,
        float* __restrict__ d, float* __restrict__ x,
        unsigned short* __restrict__ zbf, float* __restrict__ zf) {
    const int i = blockIdx.x * 256 + threadIdx.x;
    const float dv = rsqrtf(rowsum[i]);
    const float xv = 1.0f - pos[i];
    const float zv = dv * xv;
    d[i] = dv;
    x[i] = xv;
    zbf[i] = (unsigned short)f2bf(zv);
    zf[i] = zv;
}

// ---- fp8 step, 4 rows per 256-thread block: 64 MB a8 at ~6.4 TB/s = ~10us ----
__global__ __launch_bounds__(256) void k_step_fp8(
        const unsigned char* __restrict__ a8, const float* __restrict__ d,
        const float* __restrict__ xin, const unsigned short* __restrict__ zin,
        float* __restrict__ xout, unsigned short* __restrict__ zout) {
    const int r0 = blockIdx.x * 4;
    const int t  = threadIdx.x;
    const int j  = t * 32;                     // element (byte) offset in row

    uint4 pa[4][2];
#pragma unroll
    for (int r = 0; r < 4; ++r) {
        const unsigned char* arow = a8 + (size_t)(r0 + r) * NN + j;
        pa[r][0] = *(const uint4*)(arow);
        pa[r][1] = *(const uint4*)(arow + 16);
    }
    uint4 zp[4];
#pragma unroll
    for (int k = 0; k < 4; ++k)
        zp[k] = *(const uint4*)(zin + j + 8 * k);

    float acc0 = 0.0f, acc1 = 0.0f, acc2 = 0.0f, acc3 = 0.0f;
#pragma unroll
    for (int h = 0; h < 2; ++h) {
        float zf[16];
#pragma unroll
        for (int k = 0; k < 2; ++k) {
            uint4 q = zp[2 * h + k];
            zf[k * 8 + 0] = bf2f(q.x & 0xFFFFu); zf[k * 8 + 1] = bf2f(q.x >> 16);
            zf[k * 8 + 2] = bf2f(q.y & 0xFFFFu); zf[k * 8 + 3] = bf2f(q.y >> 16);
            zf[k * 8 + 4] = bf2f(q.z & 0xFFFFu); zf[k * 8 + 5] = bf2f(q.z >> 16);
            zf[k * 8 + 6] = bf2f(q.w & 0xFFFFu); zf[k * 8 + 7] = bf2f(q.w >> 16);
        }
#pragma unroll
        for (int r = 0; r < 4; ++r) {
            const uint4 p = pa[r][h];
            unsigned int w[4] = {p.x, p.y, p.z, p.w};
            float a = 0.0f;
#pragma unroll
            for (int wi = 0; wi < 4; ++wi) {
                f32x2 lo = __builtin_amdgcn_cvt_pk_f32_fp8((int)w[wi], false);
                f32x2 hi = __builtin_amdgcn_cvt_pk_f32_fp8((int)w[wi], true);
                a = fmaf(lo[0], zf[wi * 4 + 0], a);
                a = fmaf(lo[1], zf[wi * 4 + 1], a);
                a = fmaf(hi[0], zf[wi * 4 + 2], a);
                a = fmaf(hi[1], zf[wi * 4 + 3], a);
            }
            if (r == 0) acc0 += a; else if (r == 1) acc1 += a;
            else if (r == 2) acc2 += a; else acc3 += a;
        }
    }
#pragma unroll
    for (int o = 32; o > 0; o >>= 1) {
        acc0 += __shfl_down(acc0, o);
        acc1 += __shfl_down(acc1, o);
        acc2 += __shfl_down(acc2, o);
        acc3 += __shfl_down(acc3, o);
    }
    __shared__ float red[4][4];
    if ((t & 63) == 0) {
        const int w = t >> 6;
        red[0][w] = acc0; red[1][w] = acc1; red[2][w] = acc2; red[3][w] = acc3;
    }
    __syncthreads();
    if (t < 4) {
        const int row = r0 + t;
        const float y  = (red[t][0] + red[t][1]) + (red[t][2] + red[t][3]);
        const float dv = d[row];
        const float xn = ALPHA * dv * y + (1.0f - ALPHA) * xin[row];
        xout[row] = xn;
        zout[row] = (unsigned short)f2bf(dv * xn);
    }
}

// ---- Fallback step reading f32 adj + f32 z ----
__global__ __launch_bounds__(256) void k_step_f32(
        const float* __restrict__ adj, const float* __restrict__ d,
        const float* __restrict__ xin, const float* __restrict__ zin,
        float* __restrict__ xout, float* __restrict__ zout) {
    const int row = blockIdx.x;
    const int t   = threadIdx.x;
    const float* arow = adj + (size_t)row * NN;
    float acc = 0.0f;
#pragma unroll
    for (int c = 0; c < 8; ++c) {
        const int j = c * 1024 + t * 4;
        float4 a = *(const float4*)(arow + j);
        float4 z = *(const float4*)(zin + j);
        acc = fmaf(a.x, z.x, acc); acc = fmaf(a.y, z.y, acc);
        acc = fmaf(a.z, z.z, acc); acc = fmaf(a.w, z.w, acc);
    }
#pragma unroll
    for (int o = 32; o > 0; o >>= 1) acc += __shfl_down(acc, o);
    __shared__ float red[4];
    if ((t & 63) == 0) red[t >> 6] = acc;
    __syncthreads();
    if (t == 0) {
        const float y  = (red[0] + red[1]) + (red[2] + red[3]);
        const float dv = d[row];
        const float xn = ALPHA * dv * y + (1.0f - ALPHA) * xin[row];
        xout[row] = xn;
        zout[row] = dv * xn;
    }
}

// ---- updated_adj = M * adj (fallback only) ----
__global__ __launch_bounds__(256) void k_mul(
        const float* __restrict__ adj, const float* __restrict__ M,
        float* __restrict__ out) {
    size_t i = ((size_t)blockIdx.x * blockDim.x + threadIdx.x) * 4;
    const size_t stride = (size_t)gridDim.x * blockDim.x * 4;
    const size_t total = (size_t)NN * NN;
    for (; i < total; i += stride) {
        float4 a = *(const float4*)(adj + i);
        float4 m = *(const float4*)(M + i);
        float4 r;
        r.x = a.x * m.x; r.y = a.y * m.y; r.z = a.z * m.z; r.w = a.w * m.w;
        *(float4*)(out + i) = r;
    }
}

// ---- loss = -(sum pos*log(1-neg+eps)) / sum(pos), 1024 threads ----
__global__ __launch_bounds__(1024) void k_loss(
        const float* __restrict__ pos, const float* __restrict__ xfin,
        float* __restrict__ out) {
    const int t = threadIdx.x;
    float sn = 0.0f, sd = 0.0f;
#pragma unroll
    for (int c = 0; c < 8; ++c) {
        const int i4 = c * 1024 + t;
        float4 p = *(const float4*)(pos  + i4 * 4);
        float4 x = *(const float4*)(xfin + i4 * 4);
        sn += p.x * logf(1.0f - x.x + EPSV);
        sn += p.y * logf(1.0f - x.y + EPSV);
        sn += p.z * logf(1.0f - x.z + EPSV);
        sn += p.w * logf(1.0f - x.w + EPSV);
        sd += (p.x + p.y) + (p.z + p.w);
    }
#pragma unroll
    for (int o = 32; o > 0; o >>= 1) {
        sn += __shfl_down(sn, o);
        sd += __shfl_down(sd, o);
    }
    __shared__ float rn[16], rd[16];
    if ((t & 63) == 0) { rn[t >> 6] = sn; rd[t >> 6] = sd; }
    __syncthreads();
    if (t == 0) {
        float n = 0.0f, dd = 0.0f;
#pragma unroll
        for (int k = 0; k < 16; ++k) { n += rn[k]; dd += rd[k]; }
        out[0] = -n / dd;
    }
}

extern "C" void kernel_launch(void* const* d_in, const int* in_sizes, int n_in,
                              void* d_out, int out_size, void* d_ws, size_t ws_size,
                              hipStream_t stream) {
    const float* adj = (const float*)d_in[0];
    const float* pos = (const float*)d_in[1];
    const float* M   = (const float*)d_in[2];
    float* out = (float*)d_out;

    char* ws = (char*)d_ws;
    float* d_vec  = (float*)(ws + 0);
    float* rowsum = (float*)(ws + 32768);
    float* x_a    = (float*)(ws + 65536);
    float* x_b    = (float*)(ws + 98304);
    unsigned short* zb_a = (unsigned short*)(ws + 131072);
    unsigned short* zb_b = (unsigned short*)(ws + 163840);
    float* zf_a   = (float*)(ws + 196608);
    float* zf_b   = (float*)(ws + 229376);
    unsigned char* a8 = (unsigned char*)(ws + 262144);

    const size_t need_fp8 = 262144 + (size_t)NN * NN;
    const bool use_fp8 = (ws_size >= need_fp8);

    if (use_fp8) {
        k_fused_prep<<<NN, 256, 0, stream>>>(adj, M, out, a8, rowsum);
    } else {
        k_rowsum<<<NN, 256, 0, stream>>>(adj, rowsum);
    }

    k_init<<<NN / 256, 256, 0, stream>>>(rowsum, pos, d_vec, x_a, zb_a, zf_a);

    float* xi = x_a; float* xo = x_b;
    unsigned short* zbi = zb_a; unsigned short* zbo = zb_b;
    float* zfi = zf_a; float* zfo = zf_b;
    for (int s = 0; s < STEPS; ++s) {
        if (use_fp8) {
            k_step_fp8<<<NN / 4, 256, 0, stream>>>(a8, d_vec, xi, zbi, xo, zbo);
            unsigned short* tz = zbi; zbi = zbo; zbo = tz;
        } else {
            k_step_f32<<<NN, 256, 0, stream>>>(adj, d_vec, xi, zfi, xo, zfo);
            float* tz = zfi; zfi = zfo; zfo = tz;
        }
        float* t = xi; xi = xo; xo = t;
    }

    if (!use_fp8) {
        k_mul<<<2048, 256, 0, stream>>>(adj, M, out);
    }
    k_loss<<<1, 1024, 0, stream>>>(pos, xi, out + (size_t)NN * NN);
}